// Round 1
// baseline (597.534 us; speedup 1.0000x reference)
//
#include <hip/hip_runtime.h>
#include <cstdint>
#include <cstddef>
#include <cstdio>

// ---------------------------------------------------------------------------
// TransformerLayer on MI355X (gfx950), bf16 MFMA everywhere.
// b=2, L=2048, d=1024, d_ff=3072, nh=16, D_HEAD=64. All dims exact multiples
// of tile sizes -> no bounds checks.
// ---------------------------------------------------------------------------

typedef unsigned short u16;
typedef __bf16 bf16x8 __attribute__((ext_vector_type(8)));
typedef float  f32x4  __attribute__((ext_vector_type(4)));

__device__ __forceinline__ u16 f2b(float f) {
  return __builtin_bit_cast(u16, (__bf16)f);
}
__device__ __forceinline__ float b2f(u16 u) {
  return (float)__builtin_bit_cast(__bf16, u);
}

// async global->LDS, 16B per lane. LDS dest must be wave-uniform base + lane*16
// (guaranteed by our indexing: tid-linear, contiguous).
__device__ __forceinline__ void cp16(const u16* g, u16* l) {
  __builtin_amdgcn_global_load_lds(
      (__attribute__((address_space(1))) void*)(uintptr_t)g,
      (__attribute__((address_space(3))) void*)(uintptr_t)l,
      16, 0, 0);
}

// ---------------------------------------------------------------------------
// GEMM: C[M,N] = A[M,K] @ B[N,K]^T  (A row stride = lda, B row stride = K)
// A, B bf16; C fp32 (MODE 0), fp32 + residual (MODE 1), bf16 (MODE 2).
// m97 structure: 128x128 tile, BK=64, 256 thr = 4 waves, each wave 64x64.
// MFMA 16x16x32 bf16. C/D layout: col=lane&15, row=(lane>>4)*4+reg (m89/m91).
// A/B operand layout: elem[lane][j] = Mat[lane&15][(lane>>4)*8 + j].
// ---------------------------------------------------------------------------
template <int MODE>
__global__ __launch_bounds__(256) void gemm_bt(
    const u16* __restrict__ A, const u16* __restrict__ B,
    float* __restrict__ Cf, u16* __restrict__ Cb, const float* __restrict__ res,
    int M, int N, int K, int lda)
{
  __shared__ __align__(16) u16 lsA[128 * 64];
  __shared__ __align__(16) u16 lsB[128 * 64];
  const int t = threadIdx.x;
  const int w = t >> 6, lane = t & 63;
  const int wm = (w >> 1) * 64, wn = (w & 1) * 64;
  const int lr = lane & 15, quad = lane >> 4;
  const size_t rowA0 = (size_t)blockIdx.x * 128;
  const size_t rowB0 = (size_t)blockIdx.y * 128;

  f32x4 acc[4][4] = {};

  for (int k0 = 0; k0 < K; k0 += 64) {
#pragma unroll
    for (int i = 0; i < 4; ++i) {
      const int id = i * 256 + t;
      const int r = id >> 3, c = (id & 7) * 8;
      cp16(A + (rowA0 + r) * lda + k0 + c, lsA + id * 8);
      cp16(B + (rowB0 + r) * (size_t)K + k0 + c, lsB + id * 8);
    }
    __syncthreads();  // drains vmcnt (compiler emits waitcnt before barrier)
#pragma unroll
    for (int ks = 0; ks < 2; ++ks) {
      bf16x8 af[4], bfr[4];
#pragma unroll
      for (int i = 0; i < 4; ++i) {
        af[i]  = *(const bf16x8*)(lsA + (wm + i * 16 + lr) * 64 + ks * 32 + quad * 8);
        bfr[i] = *(const bf16x8*)(lsB + (wn + i * 16 + lr) * 64 + ks * 32 + quad * 8);
      }
#pragma unroll
      for (int mi = 0; mi < 4; ++mi)
#pragma unroll
        for (int ni = 0; ni < 4; ++ni)
          acc[mi][ni] = __builtin_amdgcn_mfma_f32_16x16x32_bf16(
              af[mi], bfr[ni], acc[mi][ni], 0, 0, 0);
    }
    __syncthreads();  // protect LDS from next-iter staging
  }

#pragma unroll
  for (int mi = 0; mi < 4; ++mi) {
#pragma unroll
    for (int r = 0; r < 4; ++r) {
      const size_t m = rowA0 + wm + mi * 16 + quad * 4 + r;
#pragma unroll
      for (int ni = 0; ni < 4; ++ni) {
        const size_t n = rowB0 + wn + ni * 16 + lr;
        const size_t o = m * (size_t)N + n;
        const float v = acc[mi][ni][r];
        if (MODE == 0) Cf[o] = v;
        else if (MODE == 1) Cf[o] = v + res[o];
        else Cb[o] = f2b(v);
      }
    }
  }
}

// ---------------------------------------------------------------------------
// RMSNorm: one block per row of 1024; fp32 in, bf16 out.
// ---------------------------------------------------------------------------
__global__ __launch_bounds__(256) void rmsnorm_k(
    const float* __restrict__ x, const float* __restrict__ g, u16* __restrict__ out)
{
  const int row = blockIdx.x;
  const int t = threadIdx.x;
  const float4 a = ((const float4*)(x + (size_t)row * 1024))[t];
  float ss = a.x * a.x + a.y * a.y + a.z * a.z + a.w * a.w;
#pragma unroll
  for (int o = 32; o; o >>= 1) ss += __shfl_xor(ss, o, 64);
  __shared__ float red[4];
  if ((t & 63) == 0) red[t >> 6] = ss;
  __syncthreads();
  ss = red[0] + red[1] + red[2] + red[3];
  const float r = rsqrtf(ss * (1.0f / 1024.0f) + 1e-6f);
  const float4 gg = ((const float4*)g)[t];
  ushort4 o4;
  o4.x = f2b(a.x * gg.x * r);
  o4.y = f2b(a.y * gg.y * r);
  o4.z = f2b(a.z * gg.z * r);
  o4.w = f2b(a.w * gg.w * r);
  ((ushort4*)out)[(size_t)row * 256 + t] = o4;
}

// fp32 -> bf16 weight conversion, 4 elems/thread.
__global__ __launch_bounds__(256) void cvt_bf16_k(
    const float* __restrict__ in, u16* __restrict__ out)
{
  const size_t i = (size_t)blockIdx.x * 256 + threadIdx.x;
  const float4 v = ((const float4*)in)[i];
  ushort4 o4;
  o4.x = f2b(v.x); o4.y = f2b(v.y); o4.z = f2b(v.z); o4.w = f2b(v.w);
  ((ushort4*)out)[i] = o4;
}

// ---------------------------------------------------------------------------
// QKV prep: per (n,h,l) cosine-normalize q,k with sqrt(attn_scale[h]);
// write Q,K as [head][l][64] bf16, V transposed as [head][e][L] bf16.
// Grid (L/64, nh, n), block 256.
// ---------------------------------------------------------------------------
__global__ __launch_bounds__(256) void qkv_prep_k(
    const float* __restrict__ qkv, const float* __restrict__ attn_scale,
    u16* __restrict__ Qb, u16* __restrict__ Kb, u16* __restrict__ Vt)
{
  const int l0 = blockIdx.x * 64;
  const int h  = blockIdx.y;
  const int nb = blockIdx.z;
  const int t = threadIdx.x, w = t >> 6, lane = t & 63;
  __shared__ float lsV[64][65];  // +1 pad: conflict-free transposed reads
  const float sq = sqrtf(attn_scale[h]);
  const int head = nb * 16 + h;
#pragma unroll 4
  for (int i = 0; i < 16; ++i) {
    const int lrow = i * 4 + w;
    const int l = l0 + lrow;
    const float* base = qkv + ((size_t)nb * 2048 + l) * 3072 + h * 64 + lane;
    const float qv = base[0];
    const float kv = base[1024];
    const float vv = base[2048];
    float ssq = qv * qv, ssk = kv * kv;
#pragma unroll
    for (int o = 32; o; o >>= 1) {
      ssq += __shfl_xor(ssq, o, 64);
      ssk += __shfl_xor(ssk, o, 64);
    }
    const size_t gb = ((size_t)head * 2048 + l) * 64 + lane;
    Qb[gb] = f2b(qv * sq * rsqrtf(ssq + 1e-6f));
    Kb[gb] = f2b(kv * sq * rsqrtf(ssk + 1e-6f));
    lsV[lrow][lane] = vv;
  }
  __syncthreads();
  const int e = t >> 2, p = t & 3;
  union { u16 s[16]; uint4 v[2]; } tmp;
#pragma unroll
  for (int j = 0; j < 16; ++j) tmp.s[j] = f2b(lsV[p * 16 + j][e]);
  u16* dst = Vt + ((size_t)head * 64 + e) * 2048 + l0 + p * 16;
  *(uint4*)dst = tmp.v[0];
  *(uint4*)(dst + 8) = tmp.v[1];
}

// ---------------------------------------------------------------------------
// Attention. scores bounded in [-10,10] by cosine norm -> softmax without max
// subtraction (exp<=e^10, rowsum<=2048*e^10 ~ 4.5e7, fp32-safe; matches
// reference softmax exactly up to fp error).
// Block = 64 q-rows (4 waves x 16), loops k-tiles of 64.
// S = Q·K^T via MFMA -> exp -> P to wave-private LDS (C-layout -> A-layout
// transform, m120 pattern) -> O += P·V via MFMA with Vt for contiguous B-frags.
// Grid (L/64, n*nh).
// ---------------------------------------------------------------------------
__global__ __launch_bounds__(256) void attn_k(
    const u16* __restrict__ Qb, const u16* __restrict__ Kb,
    const u16* __restrict__ Vt, u16* __restrict__ O)
{
  const int l0 = blockIdx.x * 64;
  const int head = blockIdx.y;
  const int nb = head >> 4, h = head & 15;
  const int t = threadIdx.x, w = t >> 6, lane = t & 63;
  const int lr = lane & 15, quad = lane >> 4;
  __shared__ __align__(16) u16 lsP[4][16 * 64];  // per-wave 16x64 P tile
  u16* myP = lsP[w];
  const size_t hb = (size_t)head << 17;  // head * 2048 * 64

  const int qrow = l0 + w * 16 + lr;
  const u16* qp = Qb + hb + (size_t)qrow * 64;
  const bf16x8 qf0 = *(const bf16x8*)(qp + quad * 8);
  const bf16x8 qf1 = *(const bf16x8*)(qp + 32 + quad * 8);

  f32x4 oacc[4] = {};
  float rsv[4] = {0.f, 0.f, 0.f, 0.f};

  for (int k0 = 0; k0 < 2048; k0 += 64) {
#pragma unroll
    for (int ni = 0; ni < 4; ++ni) {
      const u16* kp = Kb + hb + (size_t)(k0 + ni * 16 + lr) * 64;
      const bf16x8 b0 = *(const bf16x8*)(kp + quad * 8);
      const bf16x8 b1 = *(const bf16x8*)(kp + 32 + quad * 8);
      f32x4 s = {};
      s = __builtin_amdgcn_mfma_f32_16x16x32_bf16(qf0, b0, s, 0, 0, 0);
      s = __builtin_amdgcn_mfma_f32_16x16x32_bf16(qf1, b1, s, 0, 0, 0);
#pragma unroll
      for (int r = 0; r < 4; ++r) {
        const float p = __expf(s[r]);
        rsv[r] += p;
        myP[(quad * 4 + r) * 64 + ni * 16 + lr] = f2b(p);
      }
    }
    // wave-private LDS: same-wave DS ops are in-order; fence stops compiler
    // from reordering the typed reads before the u16 writes.
    asm volatile("" ::: "memory");
#pragma unroll
    for (int ks = 0; ks < 2; ++ks) {
      const bf16x8 af = *(const bf16x8*)(myP + lr * 64 + ks * 32 + quad * 8);
#pragma unroll
      for (int ei = 0; ei < 4; ++ei) {
        const u16* vp = Vt + hb + (size_t)(ei * 16 + lr) * 2048 + k0 + ks * 32 + quad * 8;
        const bf16x8 bv = *(const bf16x8*)vp;
        oacc[ei] = __builtin_amdgcn_mfma_f32_16x16x32_bf16(af, bv, oacc[ei], 0, 0, 0);
      }
    }
    asm volatile("" ::: "memory");  // WAR: reads done before next-iter writes
  }

  // rowsum: reduce across the 16 lanes of each quad (cols), per r.
#pragma unroll
  for (int r = 0; r < 4; ++r) {
    float v = rsv[r];
    v += __shfl_xor(v, 1, 64);
    v += __shfl_xor(v, 2, 64);
    v += __shfl_xor(v, 4, 64);
    v += __shfl_xor(v, 8, 64);
    rsv[r] = 1.0f / v;
  }
  // O layout: [n][l][d] bf16, col = h*64 + ei*16 + lr, row = l0+w*16+quad*4+r
#pragma unroll
  for (int r = 0; r < 4; ++r) {
    const int l = l0 + w * 16 + quad * 4 + r;
    u16* ob = O + ((size_t)nb * 2048 + l) * 1024 + h * 64;
#pragma unroll
    for (int ei = 0; ei < 4; ++ei)
      ob[ei * 16 + lr] = f2b(oacc[ei][r] * rsv[r]);
  }
}

// ---------------------------------------------------------------------------
// SwiGLU, in-place on u[4096][6144] bf16: u[:, :3072] = a * silu(g).
// 8 elems/thread; read a and g before writing a's slot (same thread).
// ---------------------------------------------------------------------------
__global__ __launch_bounds__(256) void swiglu_k(u16* __restrict__ u)
{
  const unsigned j = ((unsigned)blockIdx.x * 256 + threadIdx.x) * 8;
  const unsigned row = j / 3072u, col = j % 3072u;
  u16* ap = u + (size_t)row * 6144 + col;
  union { u16 s[8]; uint4 v; } a, g, hh;
  a.v = *(const uint4*)ap;
  g.v = *(const uint4*)(ap + 3072);
#pragma unroll
  for (int i = 0; i < 8; ++i) {
    const float av = b2f(a.s[i]);
    const float gv = b2f(g.s[i]);
    hh.s[i] = f2b(av * (gv / (1.0f + __expf(-gv))));
  }
  *(uint4*)ap = hh.v;
}

// ---------------------------------------------------------------------------
// Workspace layout (bytes). Total ~114 MB.
// ---------------------------------------------------------------------------
static constexpr size_t WQKV_B = 0;                            // 3072*1024*2
static constexpr size_t WOUT_B = WQKV_B + 6291456;             // 1024*1024*2
static constexpr size_t WUP_B  = WOUT_B + 2097152;             // 6144*1024*2
static constexpr size_t WDN_B  = WUP_B + 12582912;             // 1024*3072*2
static constexpr size_t XN_B   = WDN_B + 6291456;              // 4096*1024*2 (xn1 & xn2)
static constexpr size_t Q_B    = XN_B + 8388608;               // 32*2048*64*2
static constexpr size_t K_B    = Q_B + 8388608;
static constexpr size_t VT_B   = K_B + 8388608;
static constexpr size_t O_B    = VT_B + 8388608;               // 4096*1024*2
static constexpr size_t BIG_B  = O_B + 8388608;                // qkv fp32 / u bf16: 50331648
static constexpr size_t WS_NEED = BIG_B + 50331648;            // = 119537664

extern "C" void kernel_launch(void* const* d_in, const int* in_sizes, int n_in,
                              void* d_out, int out_size, void* d_ws, size_t ws_size,
                              hipStream_t stream)
{
  (void)in_sizes; (void)n_in; (void)out_size;
  if (ws_size < WS_NEED) {
    fprintf(stderr, "kernel_launch: ws_size %zu < required %zu\n", ws_size, WS_NEED);
    return;
  }
  const float* x          = (const float*)d_in[0];
  // d_in[1] = pos: unused by the reference
  const float* norm_scale = (const float*)d_in[2];
  const float* w_qkv      = (const float*)d_in[3];
  const float* attn_scale = (const float*)d_in[4];
  const float* w_out      = (const float*)d_in[5];
  const float* ff_scale   = (const float*)d_in[6];
  const float* w_up       = (const float*)d_in[7];
  const float* w_down     = (const float*)d_in[8];
  float* out = (float*)d_out;
  char* ws = (char*)d_ws;

  u16* wqkv_b = (u16*)(ws + WQKV_B);
  u16* wout_b = (u16*)(ws + WOUT_B);
  u16* wup_b  = (u16*)(ws + WUP_B);
  u16* wdn_b  = (u16*)(ws + WDN_B);
  u16* xn     = (u16*)(ws + XN_B);
  u16* Qb     = (u16*)(ws + Q_B);
  u16* Kb     = (u16*)(ws + K_B);
  u16* Vtb    = (u16*)(ws + VT_B);
  u16* Ob     = (u16*)(ws + O_B);
  float* qkvf = (float*)(ws + BIG_B);
  u16* ub     = (u16*)(ws + BIG_B);

  // weights fp32 -> bf16
  cvt_bf16_k<<<3072, 256, 0, stream>>>(w_qkv, wqkv_b);   // 3145728 el
  cvt_bf16_k<<<1024, 256, 0, stream>>>(w_out, wout_b);   // 1048576 el
  cvt_bf16_k<<<6144, 256, 0, stream>>>(w_up,  wup_b);    // 6291456 el
  cvt_bf16_k<<<3072, 256, 0, stream>>>(w_down, wdn_b);   // 3145728 el

  // xn = rmsnorm(x)
  rmsnorm_k<<<4096, 256, 0, stream>>>(x, norm_scale, xn);
  // qkv = xn @ w_qkv^T   (fp32 out)
  gemm_bt<0><<<dim3(32, 24), 256, 0, stream>>>(xn, wqkv_b, qkvf, nullptr, nullptr,
                                               4096, 3072, 1024, 1024);
  // q/k cosine norm + head-major layouts + V transpose
  qkv_prep_k<<<dim3(32, 16, 2), 256, 0, stream>>>(qkvf, attn_scale, Qb, Kb, Vtb);
  // attention -> O bf16 [n][l][d]
  attn_k<<<dim3(32, 32), 256, 0, stream>>>(Qb, Kb, Vtb, Ob);
  // x1 = O @ w_out^T + x  -> d_out (fp32)
  gemm_bt<1><<<dim3(32, 8), 256, 0, stream>>>(Ob, wout_b, out, nullptr, x,
                                              4096, 1024, 1024, 1024);
  // xn = rmsnorm(x1)
  rmsnorm_k<<<4096, 256, 0, stream>>>(out, ff_scale, xn);
  // u = xn @ w_up^T  (bf16 out, 4096x6144)
  gemm_bt<2><<<dim3(32, 48), 256, 0, stream>>>(xn, wup_b, nullptr, ub, nullptr,
                                               4096, 6144, 1024, 1024);
  // h = a * silu(g), in-place into u[:, :3072]
  swiglu_k<<<6144, 256, 0, stream>>>(ub);
  // out = h @ w_down^T + x1  (in-place residual on d_out)
  gemm_bt<1><<<dim3(32, 8), 256, 0, stream>>>(ub, wdn_b, out, nullptr, out,
                                              4096, 1024, 3072, 6144);
}

// Round 2
// 468.266 us; speedup vs baseline: 1.2761x; 1.2761x over previous
//
#include <hip/hip_runtime.h>
#include <cstdint>
#include <cstddef>
#include <cstdio>

// ---------------------------------------------------------------------------
// TransformerLayer on MI355X (gfx950), bf16 MFMA everywhere.
// b=2, L=2048, d=1024, d_ff=3072, nh=16, D_HEAD=64. All dims exact multiples
// of tile sizes -> no bounds checks.
// ---------------------------------------------------------------------------

typedef unsigned short u16;
typedef __bf16 bf16x8 __attribute__((ext_vector_type(8)));
typedef float  f32x4  __attribute__((ext_vector_type(4)));

__device__ __forceinline__ u16 f2b(float f) {
  return __builtin_bit_cast(u16, (__bf16)f);
}
__device__ __forceinline__ float b2f(u16 u) {
  return (float)__builtin_bit_cast(__bf16, u);
}

// async global->LDS, 16B per lane. LDS dest must be wave-uniform base + lane*16
// (guaranteed by our indexing: tid-linear, contiguous).
__device__ __forceinline__ void cp16(const u16* g, u16* l) {
  __builtin_amdgcn_global_load_lds(
      (__attribute__((address_space(1))) void*)(uintptr_t)g,
      (__attribute__((address_space(3))) void*)(uintptr_t)l,
      16, 0, 0);
}

// ---------------------------------------------------------------------------
// GEMM: C[M,N] = A[M,K] @ B[N,K]^T  (A row stride = lda, B row stride = K)
// A, B bf16; C fp32 (MODE 0), fp32 + residual (MODE 1), bf16 (MODE 2).
// m97 structure: 128x128 tile, BK=64, 256 thr = 4 waves, each wave 64x64.
// MFMA 16x16x32 bf16. C/D layout: col=lane&15, row=(lane>>4)*4+reg (m89/m91).
// A/B operand layout: elem[lane][j] = Mat[lane&15][(lane>>4)*8 + j].
// ---------------------------------------------------------------------------
template <int MODE>
__global__ __launch_bounds__(256) void gemm_bt(
    const u16* __restrict__ A, const u16* __restrict__ B,
    float* __restrict__ Cf, u16* __restrict__ Cb, const float* __restrict__ res,
    int M, int N, int K, int lda)
{
  __shared__ __align__(16) u16 lsA[128 * 64];
  __shared__ __align__(16) u16 lsB[128 * 64];
  const int t = threadIdx.x;
  const int w = t >> 6, lane = t & 63;
  const int wm = (w >> 1) * 64, wn = (w & 1) * 64;
  const int lr = lane & 15, quad = lane >> 4;
  const size_t rowA0 = (size_t)blockIdx.x * 128;
  const size_t rowB0 = (size_t)blockIdx.y * 128;

  f32x4 acc[4][4] = {};

  for (int k0 = 0; k0 < K; k0 += 64) {
#pragma unroll
    for (int i = 0; i < 4; ++i) {
      const int id = i * 256 + t;
      const int r = id >> 3, c = (id & 7) * 8;
      cp16(A + (rowA0 + r) * lda + k0 + c, lsA + id * 8);
      cp16(B + (rowB0 + r) * (size_t)K + k0 + c, lsB + id * 8);
    }
    __syncthreads();  // drains vmcnt (compiler emits waitcnt before barrier)
#pragma unroll
    for (int ks = 0; ks < 2; ++ks) {
      bf16x8 af[4], bfr[4];
#pragma unroll
      for (int i = 0; i < 4; ++i) {
        af[i]  = *(const bf16x8*)(lsA + (wm + i * 16 + lr) * 64 + ks * 32 + quad * 8);
        bfr[i] = *(const bf16x8*)(lsB + (wn + i * 16 + lr) * 64 + ks * 32 + quad * 8);
      }
#pragma unroll
      for (int mi = 0; mi < 4; ++mi)
#pragma unroll
        for (int ni = 0; ni < 4; ++ni)
          acc[mi][ni] = __builtin_amdgcn_mfma_f32_16x16x32_bf16(
              af[mi], bfr[ni], acc[mi][ni], 0, 0, 0);
    }
    __syncthreads();  // protect LDS from next-iter staging
  }

#pragma unroll
  for (int mi = 0; mi < 4; ++mi) {
#pragma unroll
    for (int r = 0; r < 4; ++r) {
      const size_t m = rowA0 + wm + mi * 16 + quad * 4 + r;
#pragma unroll
      for (int ni = 0; ni < 4; ++ni) {
        const size_t n = rowB0 + wn + ni * 16 + lr;
        const size_t o = m * (size_t)N + n;
        const float v = acc[mi][ni][r];
        if (MODE == 0) Cf[o] = v;
        else if (MODE == 1) Cf[o] = v + res[o];
        else Cb[o] = f2b(v);
      }
    }
  }
}

// ---------------------------------------------------------------------------
// RMSNorm: one block per row of 1024; fp32 in, bf16 out.
// ---------------------------------------------------------------------------
__global__ __launch_bounds__(256) void rmsnorm_k(
    const float* __restrict__ x, const float* __restrict__ g, u16* __restrict__ out)
{
  const int row = blockIdx.x;
  const int t = threadIdx.x;
  const float4 a = ((const float4*)(x + (size_t)row * 1024))[t];
  float ss = a.x * a.x + a.y * a.y + a.z * a.z + a.w * a.w;
#pragma unroll
  for (int o = 32; o; o >>= 1) ss += __shfl_xor(ss, o, 64);
  __shared__ float red[4];
  if ((t & 63) == 0) red[t >> 6] = ss;
  __syncthreads();
  ss = red[0] + red[1] + red[2] + red[3];
  const float r = rsqrtf(ss * (1.0f / 1024.0f) + 1e-6f);
  const float4 gg = ((const float4*)g)[t];
  ushort4 o4;
  o4.x = f2b(a.x * gg.x * r);
  o4.y = f2b(a.y * gg.y * r);
  o4.z = f2b(a.z * gg.z * r);
  o4.w = f2b(a.w * gg.w * r);
  ((ushort4*)out)[(size_t)row * 256 + t] = o4;
}

// fp32 -> bf16 weight conversion, 4 elems/thread.
__global__ __launch_bounds__(256) void cvt_bf16_k(
    const float* __restrict__ in, u16* __restrict__ out)
{
  const size_t i = (size_t)blockIdx.x * 256 + threadIdx.x;
  const float4 v = ((const float4*)in)[i];
  ushort4 o4;
  o4.x = f2b(v.x); o4.y = f2b(v.y); o4.z = f2b(v.z); o4.w = f2b(v.w);
  ((ushort4*)out)[i] = o4;
}

// ---------------------------------------------------------------------------
// QKV prep: per (n,h,l) cosine-normalize q,k with sqrt(attn_scale[h]);
// write Q,K as [head][l][64] bf16, V transposed as [head][e][L] bf16.
// Grid (L/64, nh, n), block 256.
// ---------------------------------------------------------------------------
__global__ __launch_bounds__(256) void qkv_prep_k(
    const float* __restrict__ qkv, const float* __restrict__ attn_scale,
    u16* __restrict__ Qb, u16* __restrict__ Kb, u16* __restrict__ Vt)
{
  const int l0 = blockIdx.x * 64;
  const int h  = blockIdx.y;
  const int nb = blockIdx.z;
  const int t = threadIdx.x, w = t >> 6, lane = t & 63;
  __shared__ float lsV[64][65];  // +1 pad: conflict-free transposed reads
  const float sq = sqrtf(attn_scale[h]);
  const int head = nb * 16 + h;
#pragma unroll 4
  for (int i = 0; i < 16; ++i) {
    const int lrow = i * 4 + w;
    const int l = l0 + lrow;
    const float* base = qkv + ((size_t)nb * 2048 + l) * 3072 + h * 64 + lane;
    const float qv = base[0];
    const float kv = base[1024];
    const float vv = base[2048];
    float ssq = qv * qv, ssk = kv * kv;
#pragma unroll
    for (int o = 32; o; o >>= 1) {
      ssq += __shfl_xor(ssq, o, 64);
      ssk += __shfl_xor(ssk, o, 64);
    }
    const size_t gb = ((size_t)head * 2048 + l) * 64 + lane;
    Qb[gb] = f2b(qv * sq * rsqrtf(ssq + 1e-6f));
    Kb[gb] = f2b(kv * sq * rsqrtf(ssk + 1e-6f));
    lsV[lrow][lane] = vv;
  }
  __syncthreads();
  const int e = t >> 2, p = t & 3;
  union { u16 s[16]; uint4 v[2]; } tmp;
#pragma unroll
  for (int j = 0; j < 16; ++j) tmp.s[j] = f2b(lsV[p * 16 + j][e]);
  u16* dst = Vt + ((size_t)head * 64 + e) * 2048 + l0 + p * 16;
  *(uint4*)dst = tmp.v[0];
  *(uint4*)(dst + 8) = tmp.v[1];
}

// ---------------------------------------------------------------------------
// Attention, round 2: cooperative double-buffered LDS staging of K/V tiles.
// scores bounded in [-10,10] by cosine norm -> softmax without max tracking.
// Block = 64 q-rows (4 waves x 16) x one head; loops 32 k-tiles of 64.
// Pipeline per iter: barrier (drains cur-buf staging) -> issue prefetch of
// next tile into alt buf (flies during compute) -> S=QK^T MFMA -> exp ->
// P via wave-private LDS (C->A layout) -> O += P·V MFMA from staged V.
// LDS: 2*(8K+8K) dbuf + 8K P = 40 KB -> 4 blocks/CU (matches 4 blocks/CU grid).
// Grid (L/64, n*nh) = (32, 32).
// ---------------------------------------------------------------------------
__global__ __launch_bounds__(256) void attn_k(
    const u16* __restrict__ Qb, const u16* __restrict__ Kb,
    const u16* __restrict__ Vt, u16* __restrict__ O)
{
  const int l0 = blockIdx.x * 64;
  const int head = blockIdx.y;
  const int nb = head >> 4, h = head & 15;
  const int t = threadIdx.x, w = t >> 6, lane = t & 63;
  const int lr = lane & 15, quad = lane >> 4;
  __shared__ __align__(16) u16 lsK[2][64 * 64];  // 8 KB per buf
  __shared__ __align__(16) u16 lsV[2][64 * 64];  // 8 KB per buf
  __shared__ __align__(16) u16 lsP[4][16 * 64];  // per-wave 16x64 P tile
  u16* myP = lsP[w];
  const size_t hb = (size_t)head << 17;  // head * 2048 * 64

  // staging indices: thread t covers 16B at row (t>>3), col (t&7)*8 and the
  // row+32 partner. LDS offset = t*8 u16 -> per-wave contiguous lane*16 B. ✓
  const int sr = t >> 3, sc = (t & 7) * 8;
  const u16* Kg = Kb + hb + (size_t)sr * 64 + sc;
  const u16* Vg = Vt + hb + (size_t)sr * 2048 + sc;

  const int qrow = l0 + w * 16 + lr;
  const u16* qp = Qb + hb + (size_t)qrow * 64;
  const bf16x8 qf0 = *(const bf16x8*)(qp + quad * 8);
  const bf16x8 qf1 = *(const bf16x8*)(qp + 32 + quad * 8);

  f32x4 oacc[4] = {};
  float rsv[4] = {0.f, 0.f, 0.f, 0.f};

  // prologue: stage tile 0 into buf 0
  {
    cp16(Kg, lsK[0] + t * 8);
    cp16(Kg + 32 * 64, lsK[0] + 32 * 64 + t * 8);
    cp16(Vg, lsV[0] + t * 8);
    cp16(Vg + 32 * 2048, lsV[0] + 32 * 64 + t * 8);
  }

  int cur = 0;
  for (int k0 = 0; k0 < 2048; k0 += 64) {
    __syncthreads();  // vmcnt(0) drain: buf[cur] staging complete; alt buf free
    if (k0 + 64 < 2048) {
      const int nxt = cur ^ 1;
      const u16* Kn = Kg + (size_t)(k0 + 64) * 64;
      const u16* Vn = Vg + (k0 + 64);
      cp16(Kn, lsK[nxt] + t * 8);
      cp16(Kn + 32 * 64, lsK[nxt] + 32 * 64 + t * 8);
      cp16(Vn, lsV[nxt] + t * 8);
      cp16(Vn + 32 * 2048, lsV[nxt] + 32 * 64 + t * 8);
    }
    const u16* kb = lsK[cur];
    const u16* vb = lsV[cur];

    // S = Q·K^T for this tile (16 q-rows x 64 k-cols per wave), then exp->P
#pragma unroll
    for (int ni = 0; ni < 4; ++ni) {
      const bf16x8 b0 = *(const bf16x8*)(kb + (ni * 16 + lr) * 64 + quad * 8);
      const bf16x8 b1 = *(const bf16x8*)(kb + (ni * 16 + lr) * 64 + 32 + quad * 8);
      f32x4 s = {};
      s = __builtin_amdgcn_mfma_f32_16x16x32_bf16(qf0, b0, s, 0, 0, 0);
      s = __builtin_amdgcn_mfma_f32_16x16x32_bf16(qf1, b1, s, 0, 0, 0);
#pragma unroll
      for (int r = 0; r < 4; ++r) {
        const float p = __expf(s[r]);
        rsv[r] += p;
        myP[(quad * 4 + r) * 64 + ni * 16 + lr] = f2b(p);
      }
    }
    // wave-private LDS: same-wave DS ops are in-order; fence stops compiler
    // from reordering the typed reads before the u16 writes.
    asm volatile("" ::: "memory");
#pragma unroll
    for (int ks = 0; ks < 2; ++ks) {
      const bf16x8 af = *(const bf16x8*)(myP + lr * 64 + ks * 32 + quad * 8);
#pragma unroll
      for (int ei = 0; ei < 4; ++ei) {
        const bf16x8 bv = *(const bf16x8*)(vb + (ei * 16 + lr) * 64 + ks * 32 + quad * 8);
        oacc[ei] = __builtin_amdgcn_mfma_f32_16x16x32_bf16(af, bv, oacc[ei], 0, 0, 0);
      }
    }
    asm volatile("" ::: "memory");  // WAR: P reads done before next-iter writes
    cur ^= 1;
  }

  // rowsum: reduce across the 16 lanes of each quad (cols), per r.
#pragma unroll
  for (int r = 0; r < 4; ++r) {
    float v = rsv[r];
    v += __shfl_xor(v, 1, 64);
    v += __shfl_xor(v, 2, 64);
    v += __shfl_xor(v, 4, 64);
    v += __shfl_xor(v, 8, 64);
    rsv[r] = 1.0f / v;
  }
  // O layout: [n][l][d] bf16, col = h*64 + ei*16 + lr, row = l0+w*16+quad*4+r
#pragma unroll
  for (int r = 0; r < 4; ++r) {
    const int l = l0 + w * 16 + quad * 4 + r;
    u16* ob = O + ((size_t)nb * 2048 + l) * 1024 + h * 64;
#pragma unroll
    for (int ei = 0; ei < 4; ++ei)
      ob[ei * 16 + lr] = f2b(oacc[ei][r] * rsv[r]);
  }
}

// ---------------------------------------------------------------------------
// SwiGLU, in-place on u[4096][6144] bf16: u[:, :3072] = a * silu(g).
// 8 elems/thread; read a and g before writing a's slot (same thread).
// ---------------------------------------------------------------------------
__global__ __launch_bounds__(256) void swiglu_k(u16* __restrict__ u)
{
  const unsigned j = ((unsigned)blockIdx.x * 256 + threadIdx.x) * 8;
  const unsigned row = j / 3072u, col = j % 3072u;
  u16* ap = u + (size_t)row * 6144 + col;
  union { u16 s[8]; uint4 v; } a, g, hh;
  a.v = *(const uint4*)ap;
  g.v = *(const uint4*)(ap + 3072);
#pragma unroll
  for (int i = 0; i < 8; ++i) {
    const float av = b2f(a.s[i]);
    const float gv = b2f(g.s[i]);
    hh.s[i] = f2b(av * (gv / (1.0f + __expf(-gv))));
  }
  *(uint4*)ap = hh.v;
}

// ---------------------------------------------------------------------------
// Workspace layout (bytes). Total ~114 MB.
// ---------------------------------------------------------------------------
static constexpr size_t WQKV_B = 0;                            // 3072*1024*2
static constexpr size_t WOUT_B = WQKV_B + 6291456;             // 1024*1024*2
static constexpr size_t WUP_B  = WOUT_B + 2097152;             // 6144*1024*2
static constexpr size_t WDN_B  = WUP_B + 12582912;             // 1024*3072*2
static constexpr size_t XN_B   = WDN_B + 6291456;              // 4096*1024*2 (xn1 & xn2)
static constexpr size_t Q_B    = XN_B + 8388608;               // 32*2048*64*2
static constexpr size_t K_B    = Q_B + 8388608;
static constexpr size_t VT_B   = K_B + 8388608;
static constexpr size_t O_B    = VT_B + 8388608;               // 4096*1024*2
static constexpr size_t BIG_B  = O_B + 8388608;                // qkv fp32 / u bf16: 50331648
static constexpr size_t WS_NEED = BIG_B + 50331648;            // = 119537664

extern "C" void kernel_launch(void* const* d_in, const int* in_sizes, int n_in,
                              void* d_out, int out_size, void* d_ws, size_t ws_size,
                              hipStream_t stream)
{
  (void)in_sizes; (void)n_in; (void)out_size;
  if (ws_size < WS_NEED) {
    fprintf(stderr, "kernel_launch: ws_size %zu < required %zu\n", ws_size, WS_NEED);
    return;
  }
  const float* x          = (const float*)d_in[0];
  // d_in[1] = pos: unused by the reference
  const float* norm_scale = (const float*)d_in[2];
  const float* w_qkv      = (const float*)d_in[3];
  const float* attn_scale = (const float*)d_in[4];
  const float* w_out      = (const float*)d_in[5];
  const float* ff_scale   = (const float*)d_in[6];
  const float* w_up       = (const float*)d_in[7];
  const float* w_down     = (const float*)d_in[8];
  float* out = (float*)d_out;
  char* ws = (char*)d_ws;

  u16* wqkv_b = (u16*)(ws + WQKV_B);
  u16* wout_b = (u16*)(ws + WOUT_B);
  u16* wup_b  = (u16*)(ws + WUP_B);
  u16* wdn_b  = (u16*)(ws + WDN_B);
  u16* xn     = (u16*)(ws + XN_B);
  u16* Qb     = (u16*)(ws + Q_B);
  u16* Kb     = (u16*)(ws + K_B);
  u16* Vtb    = (u16*)(ws + VT_B);
  u16* Ob     = (u16*)(ws + O_B);
  float* qkvf = (float*)(ws + BIG_B);
  u16* ub     = (u16*)(ws + BIG_B);

  // weights fp32 -> bf16
  cvt_bf16_k<<<3072, 256, 0, stream>>>(w_qkv, wqkv_b);   // 3145728 el
  cvt_bf16_k<<<1024, 256, 0, stream>>>(w_out, wout_b);   // 1048576 el
  cvt_bf16_k<<<6144, 256, 0, stream>>>(w_up,  wup_b);    // 6291456 el
  cvt_bf16_k<<<3072, 256, 0, stream>>>(w_down, wdn_b);   // 3145728 el

  // xn = rmsnorm(x)
  rmsnorm_k<<<4096, 256, 0, stream>>>(x, norm_scale, xn);
  // qkv = xn @ w_qkv^T   (fp32 out)
  gemm_bt<0><<<dim3(32, 24), 256, 0, stream>>>(xn, wqkv_b, qkvf, nullptr, nullptr,
                                               4096, 3072, 1024, 1024);
  // q/k cosine norm + head-major layouts + V transpose
  qkv_prep_k<<<dim3(32, 16, 2), 256, 0, stream>>>(qkvf, attn_scale, Qb, Kb, Vtb);
  // attention -> O bf16 [n][l][d]
  attn_k<<<dim3(32, 32), 256, 0, stream>>>(Qb, Kb, Vtb, Ob);
  // x1 = O @ w_out^T + x  -> d_out (fp32)
  gemm_bt<1><<<dim3(32, 8), 256, 0, stream>>>(Ob, wout_b, out, nullptr, x,
                                              4096, 1024, 1024, 1024);
  // xn = rmsnorm(x1)
  rmsnorm_k<<<4096, 256, 0, stream>>>(out, ff_scale, xn);
  // u = xn @ w_up^T  (bf16 out, 4096x6144)
  gemm_bt<2><<<dim3(32, 48), 256, 0, stream>>>(xn, wup_b, nullptr, ub, nullptr,
                                               4096, 6144, 1024, 1024);
  // h = a * silu(g), in-place into u[:, :3072]
  swiglu_k<<<6144, 256, 0, stream>>>(ub);
  // out = h @ w_down^T + x1  (in-place residual on d_out)
  gemm_bt<1><<<dim3(32, 8), 256, 0, stream>>>(ub, wdn_b, out, nullptr, out,
                                              4096, 1024, 3072, 6144);
}

// Round 3
// 386.336 us; speedup vs baseline: 1.5467x; 1.2121x over previous
//
#include <hip/hip_runtime.h>
#include <cstdint>
#include <cstddef>
#include <cstdio>

// ---------------------------------------------------------------------------
// TransformerLayer on MI355X (gfx950), bf16 MFMA everywhere.
// b=2, L=2048, d=1024, d_ff=3072, nh=16, D_HEAD=64.
// Round 3: XOR-swizzled LDS layouts (chunk c of row r lives at c^(r&7)) to
// kill the 16-way/8-way bank conflicts measured in round 2 (3.25e7 cycles).
// ---------------------------------------------------------------------------

typedef unsigned short u16;
typedef __bf16 bf16x8 __attribute__((ext_vector_type(8)));
typedef float  f32x4  __attribute__((ext_vector_type(4)));

__device__ __forceinline__ u16 f2b(float f) {
  return __builtin_bit_cast(u16, (__bf16)f);
}
__device__ __forceinline__ float b2f(u16 u) {
  return (float)__builtin_bit_cast(__bf16, u);
}

// async global->LDS, 16B per lane. LDS dest must be wave-uniform base + lane*16.
__device__ __forceinline__ void cp16(const u16* g, u16* l) {
  __builtin_amdgcn_global_load_lds(
      (__attribute__((address_space(1))) void*)(uintptr_t)g,
      (__attribute__((address_space(3))) void*)(uintptr_t)l,
      16, 0, 0);
}

// ---------------------------------------------------------------------------
// GEMM: C[M,N] = A[M,K] @ B[N,K]^T  (A row stride = lda, B row stride = K)
// A, B bf16; C fp32 (MODE 0), fp32 + residual (MODE 1), bf16 (MODE 2).
// 128x128 tile, BK=64, 4 waves, 16x16x32 MFMA.
// LDS tiles XOR-swizzled: physical chunk = logical ^ (row&7). Staging keeps
// lane-contiguous LDS dest (cp16 constraint); global col is permuted instead.
// Fragment reads: chunk (ks*4+quad)^(lr&7) -> even over all 8 bank groups.
// ---------------------------------------------------------------------------
template <int MODE>
__global__ __launch_bounds__(256) void gemm_bt(
    const u16* __restrict__ A, const u16* __restrict__ B,
    float* __restrict__ Cf, u16* __restrict__ Cb, const float* __restrict__ res,
    int M, int N, int K, int lda)
{
  __shared__ __align__(16) u16 lsA[128 * 64];
  __shared__ __align__(16) u16 lsB[128 * 64];
  const int t = threadIdx.x;
  const int w = t >> 6, lane = t & 63;
  const int wm = (w >> 1) * 64, wn = (w & 1) * 64;
  const int lr = lane & 15, quad = lane >> 4;
  const int cswz = lr & 7;
  const size_t rowA0 = (size_t)blockIdx.x * 128;
  const size_t rowB0 = (size_t)blockIdx.y * 128;

  f32x4 acc[4][4] = {};

  for (int k0 = 0; k0 < K; k0 += 64) {
#pragma unroll
    for (int i = 0; i < 4; ++i) {
      const int id = i * 256 + t;
      const int r = id >> 3;
      const int c = ((id & 7) ^ (r & 7)) * 8;  // swizzled source column
      cp16(A + (rowA0 + r) * lda + k0 + c, lsA + id * 8);
      cp16(B + (rowB0 + r) * (size_t)K + k0 + c, lsB + id * 8);
    }
    __syncthreads();
#pragma unroll
    for (int ks = 0; ks < 2; ++ks) {
      const int co = ((ks * 4 + quad) ^ cswz) * 8;
      bf16x8 af[4], bfr[4];
#pragma unroll
      for (int i = 0; i < 4; ++i) {
        af[i]  = *(const bf16x8*)(lsA + (wm + i * 16 + lr) * 64 + co);
        bfr[i] = *(const bf16x8*)(lsB + (wn + i * 16 + lr) * 64 + co);
      }
#pragma unroll
      for (int mi = 0; mi < 4; ++mi)
#pragma unroll
        for (int ni = 0; ni < 4; ++ni)
          acc[mi][ni] = __builtin_amdgcn_mfma_f32_16x16x32_bf16(
              af[mi], bfr[ni], acc[mi][ni], 0, 0, 0);
    }
    __syncthreads();
  }

#pragma unroll
  for (int mi = 0; mi < 4; ++mi) {
#pragma unroll
    for (int r = 0; r < 4; ++r) {
      const size_t m = rowA0 + wm + mi * 16 + quad * 4 + r;
#pragma unroll
      for (int ni = 0; ni < 4; ++ni) {
        const size_t n = rowB0 + wn + ni * 16 + lr;
        const size_t o = m * (size_t)N + n;
        const float v = acc[mi][ni][r];
        if (MODE == 0) Cf[o] = v;
        else if (MODE == 1) Cf[o] = v + res[o];
        else Cb[o] = f2b(v);
      }
    }
  }
}

// ---------------------------------------------------------------------------
// RMSNorm: one block per row of 1024; fp32 in, bf16 out.
// ---------------------------------------------------------------------------
__global__ __launch_bounds__(256) void rmsnorm_k(
    const float* __restrict__ x, const float* __restrict__ g, u16* __restrict__ out)
{
  const int row = blockIdx.x;
  const int t = threadIdx.x;
  const float4 a = ((const float4*)(x + (size_t)row * 1024))[t];
  float ss = a.x * a.x + a.y * a.y + a.z * a.z + a.w * a.w;
#pragma unroll
  for (int o = 32; o; o >>= 1) ss += __shfl_xor(ss, o, 64);
  __shared__ float red[4];
  if ((t & 63) == 0) red[t >> 6] = ss;
  __syncthreads();
  ss = red[0] + red[1] + red[2] + red[3];
  const float r = rsqrtf(ss * (1.0f / 1024.0f) + 1e-6f);
  const float4 gg = ((const float4*)g)[t];
  ushort4 o4;
  o4.x = f2b(a.x * gg.x * r);
  o4.y = f2b(a.y * gg.y * r);
  o4.z = f2b(a.z * gg.z * r);
  o4.w = f2b(a.w * gg.w * r);
  ((ushort4*)out)[(size_t)row * 256 + t] = o4;
}

// fp32 -> bf16 weight conversion, 4 elems/thread.
__global__ __launch_bounds__(256) void cvt_bf16_k(
    const float* __restrict__ in, u16* __restrict__ out)
{
  const size_t i = (size_t)blockIdx.x * 256 + threadIdx.x;
  const float4 v = ((const float4*)in)[i];
  ushort4 o4;
  o4.x = f2b(v.x); o4.y = f2b(v.y); o4.z = f2b(v.z); o4.w = f2b(v.w);
  ((ushort4*)out)[i] = o4;
}

// ---------------------------------------------------------------------------
// QKV prep (bf16 input now): per (n,h,l) cosine-normalize q,k with
// sqrt(attn_scale[h]); write Q,K as [head][l][64] bf16, V transposed as
// [head][e][L] bf16. Grid (L/64, nh, n), block 256.
// ---------------------------------------------------------------------------
__global__ __launch_bounds__(256) void qkv_prep_k(
    const u16* __restrict__ qkv, const float* __restrict__ attn_scale,
    u16* __restrict__ Qb, u16* __restrict__ Kb, u16* __restrict__ Vt)
{
  const int l0 = blockIdx.x * 64;
  const int h  = blockIdx.y;
  const int nb = blockIdx.z;
  const int t = threadIdx.x, w = t >> 6, lane = t & 63;
  __shared__ float lsV[64][65];  // +1 pad: conflict-free transposed reads
  const float sq = sqrtf(attn_scale[h]);
  const int head = nb * 16 + h;
#pragma unroll 4
  for (int i = 0; i < 16; ++i) {
    const int lrow = i * 4 + w;
    const int l = l0 + lrow;
    const u16* base = qkv + ((size_t)nb * 2048 + l) * 3072 + h * 64 + lane;
    const float qv = b2f(base[0]);
    const float kv = b2f(base[1024]);
    const float vv = b2f(base[2048]);
    float ssq = qv * qv, ssk = kv * kv;
#pragma unroll
    for (int o = 32; o; o >>= 1) {
      ssq += __shfl_xor(ssq, o, 64);
      ssk += __shfl_xor(ssk, o, 64);
    }
    const size_t gb = ((size_t)head * 2048 + l) * 64 + lane;
    Qb[gb] = f2b(qv * sq * rsqrtf(ssq + 1e-6f));
    Kb[gb] = f2b(kv * sq * rsqrtf(ssk + 1e-6f));
    lsV[lrow][lane] = vv;
  }
  __syncthreads();
  const int e = t >> 2, p = t & 3;
  union { u16 s[16]; uint4 v[2]; } tmp;
#pragma unroll
  for (int j = 0; j < 16; ++j) tmp.s[j] = f2b(lsV[p * 16 + j][e]);
  u16* dst = Vt + ((size_t)head * 64 + e) * 2048 + l0 + p * 16;
  *(uint4*)dst = tmp.v[0];
  *(uint4*)(dst + 8) = tmp.v[1];
}

// ---------------------------------------------------------------------------
// Attention, round 3: double-buffered LDS staging + XOR-swizzled tiles.
// scores bounded in [-10,10] by cosine norm -> softmax without max tracking.
// Block = 64 q-rows (4 waves x 16) x one head; loops 32 k-tiles of 64.
// LDS: 2*(8K+8K) dbuf + 8K P = 40 KB -> 4 blocks/CU. Grid (32, 32).
// All LDS tiles swizzled: chunk c of row r at c^(r&7).
// ---------------------------------------------------------------------------
__global__ __launch_bounds__(256) void attn_k(
    const u16* __restrict__ Qb, const u16* __restrict__ Kb,
    const u16* __restrict__ Vt, u16* __restrict__ O)
{
  const int l0 = blockIdx.x * 64;
  const int head = blockIdx.y;
  const int nb = head >> 4, h = head & 15;
  const int t = threadIdx.x, w = t >> 6, lane = t & 63;
  const int lr = lane & 15, quad = lane >> 4;
  const int cswz = lr & 7;
  __shared__ __align__(16) u16 lsK[2][64 * 64];
  __shared__ __align__(16) u16 lsV[2][64 * 64];
  __shared__ __align__(16) u16 lsP[4][16 * 64];
  u16* myP = lsP[w];
  const size_t hb = (size_t)head << 17;  // head * 2048 * 64

  // staging: thread t owns LDS chunk t (row t>>3, pos t&7); it loads the
  // global chunk whose logical index is (t&7)^(row&7). Rows +32 share row&7.
  const int sr = t >> 3;
  const int sc = ((t & 7) ^ (sr & 7)) * 8;
  const u16* Kg = Kb + hb + (size_t)sr * 64 + sc;
  const u16* Vg = Vt + hb + (size_t)sr * 2048 + sc;

  const int qrow = l0 + w * 16 + lr;
  const u16* qp = Qb + hb + (size_t)qrow * 64;
  const bf16x8 qf0 = *(const bf16x8*)(qp + quad * 8);
  const bf16x8 qf1 = *(const bf16x8*)(qp + 32 + quad * 8);

  f32x4 oacc[4] = {};
  float rsv[4] = {0.f, 0.f, 0.f, 0.f};

  // prologue: stage tile 0 into buf 0
  cp16(Kg, lsK[0] + t * 8);
  cp16(Kg + 32 * 64, lsK[0] + 32 * 64 + t * 8);
  cp16(Vg, lsV[0] + t * 8);
  cp16(Vg + 32 * 2048, lsV[0] + 32 * 64 + t * 8);

  int cur = 0;
  for (int k0 = 0; k0 < 2048; k0 += 64) {
    __syncthreads();  // buf[cur] staged; alt buf's readers are done
    if (k0 + 64 < 2048) {
      const int nxt = cur ^ 1;
      const u16* Kn = Kg + (size_t)(k0 + 64) * 64;
      const u16* Vn = Vg + (k0 + 64);
      cp16(Kn, lsK[nxt] + t * 8);
      cp16(Kn + 32 * 64, lsK[nxt] + 32 * 64 + t * 8);
      cp16(Vn, lsV[nxt] + t * 8);
      cp16(Vn + 32 * 2048, lsV[nxt] + 32 * 64 + t * 8);
    }
    const u16* kb = lsK[cur];
    const u16* vb = lsV[cur];

    // S = Q·K^T, exp -> P (swizzled store)
#pragma unroll
    for (int ni = 0; ni < 4; ++ni) {
      const int krow = (ni * 16 + lr) * 64;
      const bf16x8 b0 = *(const bf16x8*)(kb + krow + ((quad ^ cswz) * 8));
      const bf16x8 b1 = *(const bf16x8*)(kb + krow + (((4 + quad) ^ cswz) * 8));
      f32x4 s = {};
      s = __builtin_amdgcn_mfma_f32_16x16x32_bf16(qf0, b0, s, 0, 0, 0);
      s = __builtin_amdgcn_mfma_f32_16x16x32_bf16(qf1, b1, s, 0, 0, 0);
      const int pchunk = ni * 2 + (lr >> 3);
#pragma unroll
      for (int r = 0; r < 4; ++r) {
        const float p = __expf(s[r]);
        rsv[r] += p;
        const int prow = quad * 4 + r;
        myP[prow * 64 + ((pchunk ^ (prow & 7)) << 3) + (lane & 7)] = f2b(p);
      }
    }
    asm volatile("" ::: "memory");  // order P writes before P reads (same wave)
#pragma unroll
    for (int ks = 0; ks < 2; ++ks) {
      const bf16x8 af = *(const bf16x8*)(myP + lr * 64 + (((ks * 4 + quad) ^ cswz) << 3));
#pragma unroll
      for (int ei = 0; ei < 4; ++ei) {
        const bf16x8 bv = *(const bf16x8*)(vb + (ei * 16 + lr) * 64 + (((ks * 4 + quad) ^ cswz) << 3));
        oacc[ei] = __builtin_amdgcn_mfma_f32_16x16x32_bf16(af, bv, oacc[ei], 0, 0, 0);
      }
    }
    asm volatile("" ::: "memory");  // WAR: P reads done before next-iter writes
    cur ^= 1;
  }

  // rowsum across the 16 lr lanes (cols), per r.
#pragma unroll
  for (int r = 0; r < 4; ++r) {
    float v = rsv[r];
    v += __shfl_xor(v, 1, 64);
    v += __shfl_xor(v, 2, 64);
    v += __shfl_xor(v, 4, 64);
    v += __shfl_xor(v, 8, 64);
    rsv[r] = 1.0f / v;
  }
#pragma unroll
  for (int r = 0; r < 4; ++r) {
    const int l = l0 + w * 16 + quad * 4 + r;
    u16* ob = O + ((size_t)nb * 2048 + l) * 1024 + h * 64;
#pragma unroll
    for (int ei = 0; ei < 4; ++ei)
      ob[ei * 16 + lr] = f2b(oacc[ei][r] * rsv[r]);
  }
}

// ---------------------------------------------------------------------------
// SwiGLU, in-place on u[4096][6144] bf16: u[:, :3072] = a * silu(g).
// ---------------------------------------------------------------------------
__global__ __launch_bounds__(256) void swiglu_k(u16* __restrict__ u)
{
  const unsigned j = ((unsigned)blockIdx.x * 256 + threadIdx.x) * 8;
  const unsigned row = j / 3072u, col = j % 3072u;
  u16* ap = u + (size_t)row * 6144 + col;
  union { u16 s[8]; uint4 v; } a, g, hh;
  a.v = *(const uint4*)ap;
  g.v = *(const uint4*)(ap + 3072);
#pragma unroll
  for (int i = 0; i < 8; ++i) {
    const float av = b2f(a.s[i]);
    const float gv = b2f(g.s[i]);
    hh.s[i] = f2b(av * (gv / (1.0f + __expf(-gv))));
  }
  *(uint4*)ap = hh.v;
}

// ---------------------------------------------------------------------------
// Workspace layout (bytes).
// ---------------------------------------------------------------------------
static constexpr size_t WQKV_B = 0;                            // 3072*1024*2
static constexpr size_t WOUT_B = WQKV_B + 6291456;             // 1024*1024*2
static constexpr size_t WUP_B  = WOUT_B + 2097152;             // 6144*1024*2
static constexpr size_t WDN_B  = WUP_B + 12582912;             // 1024*3072*2
static constexpr size_t XN_B   = WDN_B + 6291456;              // 4096*1024*2
static constexpr size_t Q_B    = XN_B + 8388608;               // 32*2048*64*2
static constexpr size_t K_B    = Q_B + 8388608;
static constexpr size_t VT_B   = K_B + 8388608;
static constexpr size_t O_B    = VT_B + 8388608;               // 4096*1024*2
static constexpr size_t BIG_B  = O_B + 8388608;                // qkv bf16 / u bf16
static constexpr size_t WS_NEED = BIG_B + 50331648;            // = 119537664

extern "C" void kernel_launch(void* const* d_in, const int* in_sizes, int n_in,
                              void* d_out, int out_size, void* d_ws, size_t ws_size,
                              hipStream_t stream)
{
  (void)in_sizes; (void)n_in; (void)out_size;
  if (ws_size < WS_NEED) {
    fprintf(stderr, "kernel_launch: ws_size %zu < required %zu\n", ws_size, WS_NEED);
    return;
  }
  const float* x          = (const float*)d_in[0];
  const float* norm_scale = (const float*)d_in[2];
  const float* w_qkv      = (const float*)d_in[3];
  const float* attn_scale = (const float*)d_in[4];
  const float* w_out      = (const float*)d_in[5];
  const float* ff_scale   = (const float*)d_in[6];
  const float* w_up       = (const float*)d_in[7];
  const float* w_down     = (const float*)d_in[8];
  float* out = (float*)d_out;
  char* ws = (char*)d_ws;

  u16* wqkv_b = (u16*)(ws + WQKV_B);
  u16* wout_b = (u16*)(ws + WOUT_B);
  u16* wup_b  = (u16*)(ws + WUP_B);
  u16* wdn_b  = (u16*)(ws + WDN_B);
  u16* xn     = (u16*)(ws + XN_B);
  u16* Qb     = (u16*)(ws + Q_B);
  u16* Kb     = (u16*)(ws + K_B);
  u16* Vtb    = (u16*)(ws + VT_B);
  u16* Ob     = (u16*)(ws + O_B);
  u16* qkvb   = (u16*)(ws + BIG_B);  // qkv bf16 (25 MB), later reused for u
  u16* ub     = (u16*)(ws + BIG_B);

  // weights fp32 -> bf16
  cvt_bf16_k<<<3072, 256, 0, stream>>>(w_qkv, wqkv_b);
  cvt_bf16_k<<<1024, 256, 0, stream>>>(w_out, wout_b);
  cvt_bf16_k<<<6144, 256, 0, stream>>>(w_up,  wup_b);
  cvt_bf16_k<<<3072, 256, 0, stream>>>(w_down, wdn_b);

  // xn = rmsnorm(x)
  rmsnorm_k<<<4096, 256, 0, stream>>>(x, norm_scale, xn);
  // qkv = xn @ w_qkv^T  (bf16 out now)
  gemm_bt<2><<<dim3(32, 24), 256, 0, stream>>>(xn, wqkv_b, nullptr, qkvb, nullptr,
                                               4096, 3072, 1024, 1024);
  // q/k cosine norm + head-major layouts + V transpose
  qkv_prep_k<<<dim3(32, 16, 2), 256, 0, stream>>>(qkvb, attn_scale, Qb, Kb, Vtb);
  // attention -> O bf16 [n][l][d]
  attn_k<<<dim3(32, 32), 256, 0, stream>>>(Qb, Kb, Vtb, Ob);
  // x1 = O @ w_out^T + x  -> d_out (fp32)
  gemm_bt<1><<<dim3(32, 8), 256, 0, stream>>>(Ob, wout_b, out, nullptr, x,
                                              4096, 1024, 1024, 1024);
  // xn = rmsnorm(x1)
  rmsnorm_k<<<4096, 256, 0, stream>>>(out, ff_scale, xn);
  // u = xn @ w_up^T  (bf16 out, 4096x6144)  -- overwrites qkvb region
  gemm_bt<2><<<dim3(32, 48), 256, 0, stream>>>(xn, wup_b, nullptr, ub, nullptr,
                                               4096, 6144, 1024, 1024);
  // h = a * silu(g), in-place into u[:, :3072]
  swiglu_k<<<6144, 256, 0, stream>>>(ub);
  // out = h @ w_down^T + x1  (in-place residual on d_out)
  gemm_bt<1><<<dim3(32, 8), 256, 0, stream>>>(ub, wdn_b, out, nullptr, out,
                                              4096, 1024, 3072, 6144);
}